// Round 2
// baseline (1006.614 us; speedup 1.0000x reference)
//
#include <hip/hip_runtime.h>
#include <hip/hip_bf16.h>

#define N      4096
#define NFEAT  512
#define NHID   64
#define NHEADS 8
#define NCLASS 40
#define ALPHA  0.2f

__device__ __forceinline__ float lrelu(float v) {
    return v > 0.f ? v : ALPHA * v;
}

// ---------------- K1: Wh1[n][h*64+d] = sum_f x[n,f] * W1[h,f,d] ----------------
// grid (64 n-tiles, 8 heads), 256 threads. 64x64 C-tile, 4x4 per thread.
__global__ __launch_bounds__(256) void k1_gemm1(const float* __restrict__ x,
                                                const float* __restrict__ W1,
                                                float* __restrict__ Wh1) {
    __shared__ float As[16][64];   // [f][n]  (transposed for float4 n-reads)
    __shared__ float Bs[16][64];   // [f][d]
    const int t  = threadIdx.x;
    const int n0 = blockIdx.x * 64;
    const int h  = blockIdx.y;
    const int ti = t >> 4, tj = t & 15;
    const int an = t >> 2;            // staging: n row 0..63
    const int af = (t & 3) * 4;       // staging: f col 0,4,8,12
    const int bf = t >> 4;            // staging: f row 0..15
    const int bd = (t & 15) * 4;      // staging: d col 0..60
    float acc[4][4] = {};
    for (int f0 = 0; f0 < NFEAT; f0 += 16) {
        __syncthreads();
        float4 av = *(const float4*)&x[(size_t)(n0 + an) * NFEAT + f0 + af];
        As[af + 0][an] = av.x;
        As[af + 1][an] = av.y;
        As[af + 2][an] = av.z;
        As[af + 3][an] = av.w;
        *(float4*)&Bs[bf][bd] =
            *(const float4*)&W1[(size_t)h * NFEAT * NHID + (size_t)(f0 + bf) * NHID + bd];
        __syncthreads();
        #pragma unroll
        for (int kf = 0; kf < 16; ++kf) {
            float4 a4 = *(const float4*)&As[kf][ti * 4];
            float4 b4 = *(const float4*)&Bs[kf][tj * 4];
            acc[0][0] += a4.x * b4.x; acc[0][1] += a4.x * b4.y; acc[0][2] += a4.x * b4.z; acc[0][3] += a4.x * b4.w;
            acc[1][0] += a4.y * b4.x; acc[1][1] += a4.y * b4.y; acc[1][2] += a4.y * b4.z; acc[1][3] += a4.y * b4.w;
            acc[2][0] += a4.z * b4.x; acc[2][1] += a4.z * b4.y; acc[2][2] += a4.z * b4.z; acc[2][3] += a4.z * b4.w;
            acc[3][0] += a4.w * b4.x; acc[3][1] += a4.w * b4.y; acc[3][2] += a4.w * b4.z; acc[3][3] += a4.w * b4.w;
        }
    }
    #pragma unroll
    for (int i = 0; i < 4; ++i) {
        *(float4*)&Wh1[(size_t)(n0 + ti * 4 + i) * (NHEADS * NHID) + h * NHID + tj * 4] =
            make_float4(acc[i][0], acc[i][1], acc[i][2], acc[i][3]);
    }
}

// ---------------- K2: f1[h][n], f2[h][n] = Wh1[n, h*64: ] . a1[h,{0,1},:] -------
// one wave per (h,n); grid 8192 x 256
__global__ __launch_bounds__(256) void k2_f12(const float* __restrict__ Wh1,
                                              const float* __restrict__ a1,
                                              float* __restrict__ f1,
                                              float* __restrict__ f2) {
    const int t = threadIdx.x;
    const int lane = t & 63;
    const int u = blockIdx.x * 4 + (t >> 6);
    const int h = u >> 12;
    const int n = u & (N - 1);
    float v  = Wh1[(size_t)n * 512 + h * 64 + lane];
    float s1 = v * a1[h * 128 + lane];
    float s2 = v * a1[h * 128 + 64 + lane];
    #pragma unroll
    for (int off = 32; off >= 1; off >>= 1) {
        s1 += __shfl_xor(s1, off);
        s2 += __shfl_xor(s2, off);
    }
    if (lane == 0) { f1[h * N + n] = s1; f2[h * N + n] = s2; }
}

// ---------------- K3: layer-1 attention + ELU -> h1[n][h*64+d] -------------------
// grid (64 n-tiles, 8 heads), 256 threads. TN=64 rows, TM=128 m-tile.
// LDS exactly 64KB: wt[64][128] (swizzled) + whs[128][64].
__global__ __launch_bounds__(256) void k3_attn1(const int* __restrict__ adj1,
                                                const float* __restrict__ Wh1,
                                                const float* __restrict__ f1,
                                                const float* __restrict__ f2,
                                                float* __restrict__ h1) {
    __shared__ float wt[64][128];    // w-tile, column swizzled by (j + 4r) & 127
    __shared__ float whs[128][64];   // Wh tile [m][d]
    const int t  = threadIdx.x;
    const int n0 = blockIdx.x * 64;
    const int h  = blockIdx.y;
    const int r  = t >> 3;           // 0..31 (rows r and r+32)
    const int g  = t & 7;            // d-group: d = g*8 .. g*8+7
    const int jw = t & 127;          // fixed j for w-phase
    const int rbase = t >> 7;        // 0 or 1 (row parity in w-phase)
    float acc[2][8] = {};
    float zacc[2] = {0.f, 0.f};
    for (int m0 = 0; m0 < N; m0 += 128) {
        __syncthreads();
        float f2v = f2[h * N + m0 + jw];
        #pragma unroll
        for (int i = 0; i < 32; ++i) {
            int rr = rbase + 2 * i;
            float f1v = f1[h * N + n0 + rr];                 // wave-uniform, L1 hit
            int a = adj1[(size_t)(n0 + rr) * N + m0 + jw];
            wt[rr][(jw + 4 * rr) & 127] = a ? __expf(lrelu(f1v + f2v)) : 0.f;
        }
        #pragma unroll
        for (int i = 0; i < 8; ++i) {
            int flat4 = t + 256 * i;
            int row = flat4 >> 4;
            int c4  = (flat4 & 15) * 4;
            *(float4*)&whs[row][c4] =
                *(const float4*)&Wh1[(size_t)(m0 + row) * 512 + h * 64 + c4];
        }
        __syncthreads();
        #pragma unroll 2
        for (int jq = 0; jq < 32; ++jq) {
            int j  = jq * 4;
            int jr = (j + 4 * r) & 127;                      // swizzled, quad-contiguous
            float4 w0 = *(const float4*)&wt[r][jr];
            float4 w1 = *(const float4*)&wt[r + 32][jr];
            #pragma unroll
            for (int q = 0; q < 4; ++q) {
                float wa = (q == 0) ? w0.x : (q == 1) ? w0.y : (q == 2) ? w0.z : w0.w;
                float wb = (q == 0) ? w1.x : (q == 1) ? w1.y : (q == 2) ? w1.z : w1.w;
                float4 b0 = *(const float4*)&whs[j + q][g * 8];
                float4 b1 = *(const float4*)&whs[j + q][g * 8 + 4];
                acc[0][0] += wa * b0.x; acc[0][1] += wa * b0.y; acc[0][2] += wa * b0.z; acc[0][3] += wa * b0.w;
                acc[0][4] += wa * b1.x; acc[0][5] += wa * b1.y; acc[0][6] += wa * b1.z; acc[0][7] += wa * b1.w;
                acc[1][0] += wb * b0.x; acc[1][1] += wb * b0.y; acc[1][2] += wb * b0.z; acc[1][3] += wb * b0.w;
                acc[1][4] += wb * b1.x; acc[1][5] += wb * b1.y; acc[1][6] += wb * b1.z; acc[1][7] += wb * b1.w;
            }
            if (g == 0) {
                zacc[0] += w0.x + w0.y + w0.z + w0.w;
                zacc[1] += w1.x + w1.y + w1.z + w1.w;
            }
        }
    }
    __syncthreads();                  // wt now dead; alias row-sum buffer into it
    float* zs = &wt[0][0];
    if (g == 0) { zs[r] = zacc[0]; zs[r + 32] = zacc[1]; }
    __syncthreads();
    #pragma unroll
    for (int rw = 0; rw < 2; ++rw) {
        int rr = r + rw * 32;
        float inv = 1.f / fmaxf(zs[rr], 1e-30f);
        float o[8];
        #pragma unroll
        for (int k = 0; k < 8; ++k) {
            float v = acc[rw][k] * inv;
            o[k] = v > 0.f ? v : __expf(v) - 1.f;            // ELU (concat=True layer)
        }
        float4* dst = (float4*)&h1[(size_t)(n0 + rr) * 512 + h * 64 + g * 8];
        dst[0] = make_float4(o[0], o[1], o[2], o[3]);
        dst[1] = make_float4(o[4], o[5], o[6], o[7]);
    }
}

// ---------------- K4: Wh2[n][c] = h1[n,:] @ Wo[:,c] ------------------------------
__global__ __launch_bounds__(256) void k4_gemm2(const float* __restrict__ h1,
                                                const float* __restrict__ Wo,
                                                float* __restrict__ Wh2) {
    const int t = threadIdx.x;
    const int c = t & 63;
    const int n = blockIdx.x * 4 + (t >> 6);
    if (c < NCLASS) {
        const float* hrow = &h1[(size_t)n * 512];
        float acc = 0.f;
        #pragma unroll 8
        for (int f = 0; f < 512; ++f)
            acc += hrow[f] * Wo[f * NCLASS + c];
        Wh2[(size_t)n * NCLASS + c] = acc;
    }
}

// ---------------- K4b: f1o[n], f2o[n] -------------------------------------------
__global__ __launch_bounds__(256) void k4b_fo(const float* __restrict__ Wh2,
                                              const float* __restrict__ ao,
                                              float* __restrict__ f1o,
                                              float* __restrict__ f2o) {
    const int n = blockIdx.x * 256 + threadIdx.x;
    float s1 = 0.f, s2 = 0.f;
    #pragma unroll
    for (int c = 0; c < NCLASS; ++c) {
        float v = Wh2[(size_t)n * NCLASS + c];
        s1 += v * ao[c];
        s2 += v * ao[NCLASS + c];
    }
    f1o[n] = s1; f2o[n] = s2;
}

// ---------------- K5a: layer-2 attention partials over m-chunks ------------------
// grid (64 n-tiles, 8 m-chunks), 256 threads. TN=64 rows, chunk = 512 m (4 tiles).
__global__ __launch_bounds__(256) void k5a_attn2(const int* __restrict__ adj0,
                                                 const float* __restrict__ Wh2,
                                                 const float* __restrict__ f1o,
                                                 const float* __restrict__ f2o,
                                                 float* __restrict__ pacc,
                                                 float* __restrict__ pz) {
    __shared__ float wt[64][128];     // swizzled like k3
    __shared__ float whs[NCLASS][132];// transposed Wh2 tile [c][m], padded
    __shared__ float f1s[64];
    const int t  = threadIdx.x;
    const int n0 = blockIdx.x * 64;
    const int chunk = blockIdx.y;
    const int mbase = chunk * 512;
    if (t < 64) f1s[t] = f1o[n0 + t];
    const int r  = t >> 3;
    const int g  = t & 7;
    const int c0 = g * 5;             // 8 groups x 5 classes
    const int jw = t & 127;
    const int rbase = t >> 7;
    float acc[2][5] = {};
    float zacc[2] = {0.f, 0.f};
    for (int mt = 0; mt < 4; ++mt) {
        int m0 = mbase + mt * 128;
        __syncthreads();
        float f2v = f2o[m0 + jw];
        #pragma unroll
        for (int i = 0; i < 32; ++i) {
            int rr = rbase + 2 * i;
            int a = adj0[(size_t)(n0 + rr) * N + m0 + jw];
            wt[rr][(jw + 4 * rr) & 127] = a ? __expf(lrelu(f1s[rr] + f2v)) : 0.f;
        }
        #pragma unroll
        for (int i = 0; i < 20; ++i) {
            int flat = t + 256 * i;                          // 128*40 = 5120 elems
            int row = flat / NCLASS;
            int cc  = flat - row * NCLASS;
            whs[cc][row] = Wh2[(size_t)(m0 + row) * NCLASS + cc];
        }
        __syncthreads();
        #pragma unroll 2
        for (int jq = 0; jq < 32; ++jq) {
            int j  = jq * 4;
            int jr = (j + 4 * r) & 127;
            float4 w0 = *(const float4*)&wt[r][jr];
            float4 w1 = *(const float4*)&wt[r + 32][jr];
            #pragma unroll
            for (int k = 0; k < 5; ++k) {
                float4 b = *(const float4*)&whs[c0 + k][j];
                acc[0][k] += w0.x * b.x + w0.y * b.y + w0.z * b.z + w0.w * b.w;
                acc[1][k] += w1.x * b.x + w1.y * b.y + w1.z * b.z + w1.w * b.w;
            }
            if (g == 0) {
                zacc[0] += w0.x + w0.y + w0.z + w0.w;
                zacc[1] += w1.x + w1.y + w1.z + w1.w;
            }
        }
    }
    #pragma unroll
    for (int rw = 0; rw < 2; ++rw) {
        int n = n0 + r + rw * 32;
        #pragma unroll
        for (int k = 0; k < 5; ++k)
            pacc[((size_t)chunk * N + n) * NCLASS + c0 + k] = acc[rw][k];
        if (g == 0) pz[(size_t)chunk * N + n] = zacc[rw];
    }
}

// ---------------- K5b: reduce chunks, ELU, log_softmax, f32 store ---------------
__global__ __launch_bounds__(256) void k5b_final(const float* __restrict__ pacc,
                                                 const float* __restrict__ pz,
                                                 float* __restrict__ out) {
    const int t = threadIdx.x;
    const int lane = t & 63;
    const int n = blockIdx.x * 4 + (t >> 6);
    float s = 0.f, Z = 0.f;
    #pragma unroll
    for (int ch = 0; ch < 8; ++ch) {
        Z += pz[(size_t)ch * N + n];
        if (lane < NCLASS) s += pacc[((size_t)ch * N + n) * NCLASS + lane];
    }
    float v;
    if (lane < NCLASS) {
        v = s / fmaxf(Z, 1e-30f);
        v = v > 0.f ? v : __expf(v) - 1.f;                   // outer ELU
    } else {
        v = -INFINITY;
    }
    float mx = v;
    #pragma unroll
    for (int off = 32; off >= 1; off >>= 1) mx = fmaxf(mx, __shfl_xor(mx, off));
    float ex = (lane < NCLASS) ? __expf(v - mx) : 0.f;
    #pragma unroll
    for (int off = 32; off >= 1; off >>= 1) ex += __shfl_xor(ex, off);
    float lse = mx + __logf(ex);
    if (lane < NCLASS) out[(size_t)n * NCLASS + lane] = v - lse;
}

// ---------------------------------------------------------------------------------
extern "C" void kernel_launch(void* const* d_in, const int* in_sizes, int n_in,
                              void* d_out, int out_size, void* d_ws, size_t ws_size,
                              hipStream_t stream) {
    const float* x   = (const float*)d_in[0];
    const int*   adj = (const int*)d_in[1];
    const float* W1  = (const float*)d_in[2];
    const float* a1  = (const float*)d_in[3];
    const float* Wo  = (const float*)d_in[4];
    const float* ao  = (const float*)d_in[5];

    float* ws   = (float*)d_ws;
    float* Wh1  = ws;                       // 4096*512
    float* h1   = Wh1 + 2097152;            // 4096*512
    float* f1   = h1 + 2097152;             // 8*4096
    float* f2   = f1 + 32768;               // 8*4096
    float* Wh2  = f2 + 32768;               // 4096*40
    float* f1o  = Wh2 + 163840;             // 4096
    float* f2o  = f1o + 4096;               // 4096
    float* pacc = f2o + 4096;               // 8*4096*40
    float* pz   = pacc + 1310720;           // 8*4096
    // total: 5,775,360 floats = ~22 MB of d_ws

    const int* adj0 = adj;                  // layer-2 mask
    const int* adj1 = adj + (size_t)N * N;  // layer-1 mask

    hipLaunchKernelGGL(k1_gemm1, dim3(64, 8), dim3(256), 0, stream, x, W1, Wh1);
    hipLaunchKernelGGL(k2_f12,   dim3(8192),  dim3(256), 0, stream, Wh1, a1, f1, f2);
    hipLaunchKernelGGL(k3_attn1, dim3(64, 8), dim3(256), 0, stream, adj1, Wh1, f1, f2, h1);
    hipLaunchKernelGGL(k4_gemm2, dim3(1024),  dim3(256), 0, stream, h1, Wo, Wh2);
    hipLaunchKernelGGL(k4b_fo,   dim3(16),    dim3(256), 0, stream, Wh2, ao, f1o, f2o);
    hipLaunchKernelGGL(k5a_attn2,dim3(64, 8), dim3(256), 0, stream, adj0, Wh2, f1o, f2o, pacc, pz);
    hipLaunchKernelGGL(k5b_final,dim3(1024),  dim3(256), 0, stream, pacc, pz, (float*)d_out);
}

// Round 4
// 802.633 us; speedup vs baseline: 1.2541x; 1.2541x over previous
//
#include <hip/hip_runtime.h>
#include <hip/hip_bf16.h>

#define N      4096
#define NFEAT  512
#define NHID   64
#define NHEADS 8
#define NCLASS 40
#define ALPHA  0.2f

typedef unsigned short u16;
typedef unsigned int   u32;
typedef __attribute__((ext_vector_type(8))) short bf16x8;
typedef __attribute__((ext_vector_type(4))) float f32x4;

__device__ __forceinline__ float lrelu(float v) {
    return v > 0.f ? v : ALPHA * v;
}
// f32 -> bf16 bits, round-to-nearest-even (inputs are finite)
__device__ __forceinline__ u16 f2b(float f) {
    u32 u = __float_as_uint(f);
    return (u16)((u + 0x7FFFu + ((u >> 16) & 1u)) >> 16);
}

// ---------------- K1: Wh1[n][h*64+d] = sum_f x[n,f] * W1[h,f,d]  (f32, unchanged) --
__global__ __launch_bounds__(256) void k1_gemm1(const float* __restrict__ x,
                                                const float* __restrict__ W1,
                                                float* __restrict__ Wh1) {
    __shared__ float As[16][64];
    __shared__ float Bs[16][64];
    const int t  = threadIdx.x;
    const int n0 = blockIdx.x * 64;
    const int h  = blockIdx.y;
    const int ti = t >> 4, tj = t & 15;
    const int an = t >> 2;
    const int af = (t & 3) * 4;
    const int bf = t >> 4;
    const int bd = (t & 15) * 4;
    float acc[4][4] = {};
    for (int f0 = 0; f0 < NFEAT; f0 += 16) {
        __syncthreads();
        float4 av = *(const float4*)&x[(size_t)(n0 + an) * NFEAT + f0 + af];
        As[af + 0][an] = av.x;
        As[af + 1][an] = av.y;
        As[af + 2][an] = av.z;
        As[af + 3][an] = av.w;
        *(float4*)&Bs[bf][bd] =
            *(const float4*)&W1[(size_t)h * NFEAT * NHID + (size_t)(f0 + bf) * NHID + bd];
        __syncthreads();
        #pragma unroll
        for (int kf = 0; kf < 16; ++kf) {
            float4 a4 = *(const float4*)&As[kf][ti * 4];
            float4 b4 = *(const float4*)&Bs[kf][tj * 4];
            acc[0][0] += a4.x * b4.x; acc[0][1] += a4.x * b4.y; acc[0][2] += a4.x * b4.z; acc[0][3] += a4.x * b4.w;
            acc[1][0] += a4.y * b4.x; acc[1][1] += a4.y * b4.y; acc[1][2] += a4.y * b4.z; acc[1][3] += a4.y * b4.w;
            acc[2][0] += a4.z * b4.x; acc[2][1] += a4.z * b4.y; acc[2][2] += a4.z * b4.z; acc[2][3] += a4.z * b4.w;
            acc[3][0] += a4.w * b4.x; acc[3][1] += a4.w * b4.y; acc[3][2] += a4.w * b4.z; acc[3][3] += a4.w * b4.w;
        }
    }
    #pragma unroll
    for (int i = 0; i < 4; ++i) {
        *(float4*)&Wh1[(size_t)(n0 + ti * 4 + i) * (NHEADS * NHID) + h * NHID + tj * 4] =
            make_float4(acc[i][0], acc[i][1], acc[i][2], acc[i][3]);
    }
}

// ---------------- K2: f1/f2 row-dots (unchanged) --------------------------------
__global__ __launch_bounds__(256) void k2_f12(const float* __restrict__ Wh1,
                                              const float* __restrict__ a1,
                                              float* __restrict__ f1,
                                              float* __restrict__ f2) {
    const int t = threadIdx.x;
    const int lane = t & 63;
    const int u = blockIdx.x * 4 + (t >> 6);
    const int h = u >> 12;
    const int n = u & (N - 1);
    float v  = Wh1[(size_t)n * 512 + h * 64 + lane];
    float s1 = v * a1[h * 128 + lane];
    float s2 = v * a1[h * 128 + 64 + lane];
    #pragma unroll
    for (int off = 32; off >= 1; off >>= 1) {
        s1 += __shfl_xor(s1, off);
        s2 += __shfl_xor(s2, off);
    }
    if (lane == 0) { f1[h * N + n] = s1; f2[h * N + n] = s2; }
}

// ---------------- K2T: Wh1 f32 [n][h*64+d] -> Wh1T bf16 [h][d][m] ---------------
// grid (64 m-blocks, 8 heads) x 256
__global__ __launch_bounds__(256) void k2t_transpose(const float* __restrict__ Wh1,
                                                     u16* __restrict__ Wh1T) {
    __shared__ float ts[64 * 68];   // [m][d], pitch 68
    const int t  = threadIdx.x;
    const int m0 = blockIdx.x * 64;
    const int h  = blockIdx.y;
    #pragma unroll
    for (int i = 0; i < 4; ++i) {
        int flat = t + 256 * i;                 // 1024 float4 chunks
        int row = flat >> 4;                    // m-local 0..63
        int c4  = (flat & 15) * 4;              // d 0..60
        *(float4*)&ts[row * 68 + c4] =
            *(const float4*)&Wh1[(size_t)(m0 + row) * 512 + h * 64 + c4];
    }
    __syncthreads();
    const int d  = t >> 2;                      // 0..63
    const int ms = (t & 3) * 16;                // m-chunk base
    u32 p[8];
    #pragma unroll
    for (int j = 0; j < 8; ++j) {
        float v0 = ts[(ms + 2 * j) * 68 + d];
        float v1 = ts[(ms + 2 * j + 1) * 68 + d];
        p[j] = (u32)f2b(v0) | ((u32)f2b(v1) << 16);
    }
    u32* dst = (u32*)&Wh1T[((size_t)(h * 64 + d)) * 4096 + m0 + ms];
    *(uint4*)dst       = make_uint4(p[0], p[1], p[2], p[3]);
    *(uint4*)(dst + 4) = make_uint4(p[4], p[5], p[6], p[7]);
}

// ---------------- K3: layer-1 attention via MFMA + ELU -> h1 --------------------
// grid (64 n-tiles, 8 heads) x 256 (4 waves; wave w owns rows w*16..w*16+15)
// A = w (exp-masked scores) bf16 [64][128]; B = Wh1T tile bf16 [d][m]; ones-col @ d=64.
__global__ __launch_bounds__(256) void k3_attn1(const int* __restrict__ adj1,
                                                const u16* __restrict__ Wh1T,
                                                const float* __restrict__ f1,
                                                const float* __restrict__ f2,
                                                float* __restrict__ h1) {
    __shared__ u16  wbf[64 * 136];    // A-tile, pitch 136 (=128+8 pad: conflict-min b128 frags)
    __shared__ u16  whT[80 * 136];    // B-tile rows d=0..79 (64 data, 64=ones, 65..79 junk)
    __shared__ float f1s[64];
    const int t     = threadIdx.x;
    const int n0    = blockIdx.x * 64;
    const int h     = blockIdx.y;
    const int lane  = t & 63;
    const int wrow  = (t >> 6) * 16;          // wave's n-row base
    const int jw    = t & 127;                // mask-gen column
    const int rbase = t >> 7;                 // mask-gen row parity
    // init: f1 stage + ones/zero rows (rows 65..79 junk is fine; zero anyway)
    if (t < 64) f1s[t] = f1[h * N + n0 + t];
    #pragma unroll
    for (int i = 0; i < 9; ++i) {
        int flat = t + 256 * i;               // 16*136 = 2176
        if (flat < 16 * 136) {
            int row = 64 + flat / 136;
            whT[row * 136 + (flat % 136)] = (row == 64) ? (u16)0x3F80 : (u16)0;
        }
    }
    f32x4 acc[5];
    #pragma unroll
    for (int df = 0; df < 5; ++df)
        #pragma unroll
        for (int r = 0; r < 4; ++r) acc[df][r] = 0.f;
    __syncthreads();

    for (int m0 = 0; m0 < N; m0 += 128) {
        // ---- stage: mask-gen -> wbf (bf16), Wh1T tile -> whT ----
        float f2v = f2[h * N + m0 + jw];
        #pragma unroll
        for (int i = 0; i < 32; ++i) {
            int rr = rbase + 2 * i;
            int a = adj1[(size_t)(n0 + rr) * N + m0 + jw];
            float w = a ? __expf(lrelu(f1s[rr] + f2v)) : 0.f;
            wbf[rr * 136 + jw] = f2b(w);
        }
        #pragma unroll
        for (int i = 0; i < 4; ++i) {
            int flat = t + 256 * i;           // 64 rows x 16 chunks
            int row = flat >> 4;
            int c8  = (flat & 15) * 8;
            *(uint4*)&whT[row * 136 + c8] =
                *(const uint4*)&Wh1T[((size_t)(h * 64 + row)) * 4096 + m0 + c8];
        }
        __syncthreads();
        // ---- compute: 4 K-steps x 5 d-frags ----
        const int ar   = wrow + (lane & 15);
        const int koff = (lane >> 4) * 8;
        #pragma unroll
        for (int ks = 0; ks < 4; ++ks) {
            int k0 = ks * 32 + koff;
            bf16x8 a = *(const bf16x8*)&wbf[ar * 136 + k0];
            #pragma unroll
            for (int df = 0; df < 5; ++df) {
                bf16x8 b = *(const bf16x8*)&whT[(df * 16 + (lane & 15)) * 136 + k0];
                acc[df] = __builtin_amdgcn_mfma_f32_16x16x32_bf16(a, b, acc[df], 0, 0, 0);
            }
        }
        __syncthreads();
    }
    // ---- epilogue: normalize by ones-column (d=64, lanes with lane&15==0), ELU ----
    #pragma unroll
    for (int r = 0; r < 4; ++r) {
        float z = __shfl(acc[4][r], lane & 48);        // broadcast col-64 within 16-group
        float invz = 1.f / fmaxf(z, 1e-30f);
        int n = n0 + wrow + (lane >> 4) * 4 + r;
        #pragma unroll
        for (int df = 0; df < 4; ++df) {
            float v = acc[df][r] * invz;
            float o = v > 0.f ? v : __expf(v) - 1.f;   // ELU
            h1[(size_t)n * 512 + h * 64 + df * 16 + (lane & 15)] = o;
        }
    }
}

// ---------------- K4: Wh2[n][c] = h1[n,:] @ Wo[:,c]  (f32, unchanged) ------------
__global__ __launch_bounds__(256) void k4_gemm2(const float* __restrict__ h1,
                                                const float* __restrict__ Wo,
                                                float* __restrict__ Wh2) {
    const int t = threadIdx.x;
    const int c = t & 63;
    const int n = blockIdx.x * 4 + (t >> 6);
    if (c < NCLASS) {
        const float* hrow = &h1[(size_t)n * 512];
        float acc = 0.f;
        #pragma unroll 8
        for (int f = 0; f < 512; ++f)
            acc += hrow[f] * Wo[f * NCLASS + c];
        Wh2[(size_t)n * NCLASS + c] = acc;
    }
}

// ---------------- K4b: f1o/f2o + Wh2T bf16 [c][n] --------------------------------
__global__ __launch_bounds__(256) void k4b_fo(const float* __restrict__ Wh2,
                                              const float* __restrict__ ao,
                                              float* __restrict__ f1o,
                                              float* __restrict__ f2o,
                                              u16* __restrict__ Wh2T) {
    const int n = blockIdx.x * 256 + threadIdx.x;
    float s1 = 0.f, s2 = 0.f;
    #pragma unroll
    for (int c = 0; c < NCLASS; ++c) {
        float v = Wh2[(size_t)n * NCLASS + c];
        s1 += v * ao[c];
        s2 += v * ao[NCLASS + c];
        Wh2T[(size_t)c * 4096 + n] = f2b(v);
    }
    f1o[n] = s1; f2o[n] = s2;
}

// ---------------- K5a: layer-2 attention partials via MFMA -----------------------
// grid (64 n-tiles, 8 m-chunks) x 256. d-frags: 0..39 data, 48 = ones col.
__global__ __launch_bounds__(256) void k5a_attn2(const int* __restrict__ adj0,
                                                 const u16* __restrict__ Wh2T,
                                                 const float* __restrict__ f1o,
                                                 const float* __restrict__ f2o,
                                                 float* __restrict__ pacc,
                                                 float* __restrict__ pz) {
    __shared__ u16  wbf[64 * 136];
    __shared__ u16  whT[64 * 136];    // rows 0..39 data, 48 ones, others zero
    __shared__ float f1s[64];
    const int t     = threadIdx.x;
    const int n0    = blockIdx.x * 64;
    const int chunk = blockIdx.y;
    const int mbase = chunk * 512;
    const int lane  = t & 63;
    const int wrow  = (t >> 6) * 16;
    const int jw    = t & 127;
    const int rbase = t >> 7;
    if (t < 64) f1s[t] = f1o[n0 + t];
    #pragma unroll
    for (int i = 0; i < 13; ++i) {
        int flat = t + 256 * i;               // rows 40..63: 24*136 = 3264
        if (flat < 24 * 136) {
            int row = 40 + flat / 136;
            whT[row * 136 + (flat % 136)] = (row == 48) ? (u16)0x3F80 : (u16)0;
        }
    }
    f32x4 acc[4];
    #pragma unroll
    for (int df = 0; df < 4; ++df)
        #pragma unroll
        for (int r = 0; r < 4; ++r) acc[df][r] = 0.f;
    __syncthreads();

    for (int mt = 0; mt < 4; ++mt) {
        int m0 = mbase + mt * 128;
        float f2v = f2o[m0 + jw];
        #pragma unroll
        for (int i = 0; i < 32; ++i) {
            int rr = rbase + 2 * i;
            int a = adj0[(size_t)(n0 + rr) * N + m0 + jw];
            float w = a ? __expf(lrelu(f1s[rr] + f2v)) : 0.f;
            wbf[rr * 136 + jw] = f2b(w);
        }
        #pragma unroll
        for (int i = 0; i < 3; ++i) {
            int flat = t + 256 * i;           // 40 rows x 16 chunks = 640
            if (flat < 640) {
                int row = flat >> 4;
                int c8  = (flat & 15) * 8;
                *(uint4*)&whT[row * 136 + c8] =
                    *(const uint4*)&Wh2T[(size_t)row * 4096 + m0 + c8];
            }
        }
        __syncthreads();
        const int ar   = wrow + (lane & 15);
        const int koff = (lane >> 4) * 8;
        #pragma unroll
        for (int ks = 0; ks < 4; ++ks) {
            int k0 = ks * 32 + koff;
            bf16x8 a = *(const bf16x8*)&wbf[ar * 136 + k0];
            #pragma unroll
            for (int df = 0; df < 4; ++df) {
                bf16x8 b = *(const bf16x8*)&whT[(df * 16 + (lane & 15)) * 136 + k0];
                acc[df] = __builtin_amdgcn_mfma_f32_16x16x32_bf16(a, b, acc[df], 0, 0, 0);
            }
        }
        __syncthreads();
    }
    // store raw partials (numerator cols 0..39, denominator col 48)
    #pragma unroll
    for (int r = 0; r < 4; ++r) {
        int n = n0 + wrow + (lane >> 4) * 4 + r;
        float z = __shfl(acc[3][r], lane & 48);
        if ((lane & 15) == 0) pz[(size_t)chunk * N + n] = z;
        #pragma unroll
        for (int df = 0; df < 3; ++df) {
            int c = df * 16 + (lane & 15);
            if (c < NCLASS)
                pacc[((size_t)chunk * N + n) * NCLASS + c] = acc[df][r];
        }
    }
}

// ---------------- K5b: reduce chunks, ELU, log_softmax, f32 store ---------------
__global__ __launch_bounds__(256) void k5b_final(const float* __restrict__ pacc,
                                                 const float* __restrict__ pz,
                                                 float* __restrict__ out) {
    const int t = threadIdx.x;
    const int lane = t & 63;
    const int n = blockIdx.x * 4 + (t >> 6);
    float s = 0.f, Z = 0.f;
    #pragma unroll
    for (int ch = 0; ch < 8; ++ch) {
        Z += pz[(size_t)ch * N + n];
        if (lane < NCLASS) s += pacc[((size_t)ch * N + n) * NCLASS + lane];
    }
    float v;
    if (lane < NCLASS) {
        v = s / fmaxf(Z, 1e-30f);
        v = v > 0.f ? v : __expf(v) - 1.f;
    } else {
        v = -INFINITY;
    }
    float mx = v;
    #pragma unroll
    for (int off = 32; off >= 1; off >>= 1) mx = fmaxf(mx, __shfl_xor(mx, off));
    float ex = (lane < NCLASS) ? __expf(v - mx) : 0.f;
    #pragma unroll
    for (int off = 32; off >= 1; off >>= 1) ex += __shfl_xor(ex, off);
    float lse = mx + __logf(ex);
    if (lane < NCLASS) out[(size_t)n * NCLASS + lane] = v - lse;
}

// ---------------------------------------------------------------------------------
extern "C" void kernel_launch(void* const* d_in, const int* in_sizes, int n_in,
                              void* d_out, int out_size, void* d_ws, size_t ws_size,
                              hipStream_t stream) {
    const float* x   = (const float*)d_in[0];
    const int*   adj = (const int*)d_in[1];
    const float* W1  = (const float*)d_in[2];
    const float* a1  = (const float*)d_in[3];
    const float* Wo  = (const float*)d_in[4];
    const float* ao  = (const float*)d_in[5];

    float* ws   = (float*)d_ws;
    float* Wh1  = ws;                        // 2,097,152 f32
    float* h1   = Wh1 + 2097152;             // 2,097,152 f32
    float* f1   = h1 + 2097152;              // 32,768
    float* f2   = f1 + 32768;                // 32,768
    float* Wh2  = f2 + 32768;                // 163,840
    float* f1o  = Wh2 + 163840;              // 4,096
    float* f2o  = f1o + 4096;                // 4,096
    float* pacc = f2o + 4096;                // 1,310,720
    float* pz   = pacc + 1310720;            // 32,768
    u16*   Wh1T = (u16*)(pz + 32768);        // 8*64*4096 u16 = 1,048,576 f32-equiv
    u16*   Wh2T = Wh1T + 2097152;            // 40*4096 u16
    // total ~ 6.9M floats ~ 27.5 MB of d_ws

    const int* adj0 = adj;                   // layer-2 mask
    const int* adj1 = adj + (size_t)N * N;   // layer-1 mask

    hipLaunchKernelGGL(k1_gemm1,      dim3(64, 8), dim3(256), 0, stream, x, W1, Wh1);
    hipLaunchKernelGGL(k2_f12,        dim3(8192),  dim3(256), 0, stream, Wh1, a1, f1, f2);
    hipLaunchKernelGGL(k2t_transpose, dim3(64, 8), dim3(256), 0, stream, Wh1, Wh1T);
    hipLaunchKernelGGL(k3_attn1,      dim3(64, 8), dim3(256), 0, stream, adj1, Wh1T, f1, f2, h1);
    hipLaunchKernelGGL(k4_gemm2,      dim3(1024),  dim3(256), 0, stream, h1, Wo, Wh2);
    hipLaunchKernelGGL(k4b_fo,        dim3(16),    dim3(256), 0, stream, Wh2, ao, f1o, f2o, Wh2T);
    hipLaunchKernelGGL(k5a_attn2,     dim3(64, 8), dim3(256), 0, stream, adj0, Wh2T, f1o, f2o, pacc, pz);
    hipLaunchKernelGGL(k5b_final,     dim3(1024),  dim3(256), 0, stream, pacc, pz, (float*)d_out);
}

// Round 5
// 348.369 us; speedup vs baseline: 2.8895x; 2.3040x over previous
//
#include <hip/hip_runtime.h>
#include <hip/hip_bf16.h>

#define N      4096
#define NFEAT  512
#define NHID   64
#define NHEADS 8
#define NCLASS 40
#define ALPHA  0.2f

typedef unsigned short u16;
typedef unsigned int   u32;
typedef __attribute__((ext_vector_type(8))) short bf16x8;
typedef __attribute__((ext_vector_type(4))) float f32x4;

__device__ __forceinline__ float lrelu(float v) {
    return v > 0.f ? v : ALPHA * v;
}
// f32 -> bf16 bits, round-to-nearest-even (inputs are finite)
__device__ __forceinline__ u16 f2b(float f) {
    u32 u = __float_as_uint(f);
    return (u16)((u + 0x7FFFu + ((u >> 16) & 1u)) >> 16);
}

// ---------------- K1: Wh1[n][h*64+d] = sum_f x[n,f] * W1[h,f,d]  (f32) ----------
__global__ __launch_bounds__(256) void k1_gemm1(const float* __restrict__ x,
                                                const float* __restrict__ W1,
                                                float* __restrict__ Wh1) {
    __shared__ float As[16][64];
    __shared__ float Bs[16][64];
    const int t  = threadIdx.x;
    const int n0 = blockIdx.x * 64;
    const int h  = blockIdx.y;
    const int ti = t >> 4, tj = t & 15;
    const int an = t >> 2;
    const int af = (t & 3) * 4;
    const int bf = t >> 4;
    const int bd = (t & 15) * 4;
    float acc[4][4] = {};
    for (int f0 = 0; f0 < NFEAT; f0 += 16) {
        __syncthreads();
        float4 av = *(const float4*)&x[(size_t)(n0 + an) * NFEAT + f0 + af];
        As[af + 0][an] = av.x;
        As[af + 1][an] = av.y;
        As[af + 2][an] = av.z;
        As[af + 3][an] = av.w;
        *(float4*)&Bs[bf][bd] =
            *(const float4*)&W1[(size_t)h * NFEAT * NHID + (size_t)(f0 + bf) * NHID + bd];
        __syncthreads();
        #pragma unroll
        for (int kf = 0; kf < 16; ++kf) {
            float4 a4 = *(const float4*)&As[kf][ti * 4];
            float4 b4 = *(const float4*)&Bs[kf][tj * 4];
            acc[0][0] += a4.x * b4.x; acc[0][1] += a4.x * b4.y; acc[0][2] += a4.x * b4.z; acc[0][3] += a4.x * b4.w;
            acc[1][0] += a4.y * b4.x; acc[1][1] += a4.y * b4.y; acc[1][2] += a4.y * b4.z; acc[1][3] += a4.y * b4.w;
            acc[2][0] += a4.z * b4.x; acc[2][1] += a4.z * b4.y; acc[2][2] += a4.z * b4.z; acc[2][3] += a4.z * b4.w;
            acc[3][0] += a4.w * b4.x; acc[3][1] += a4.w * b4.y; acc[3][2] += a4.w * b4.z; acc[3][3] += a4.w * b4.w;
        }
    }
    #pragma unroll
    for (int i = 0; i < 4; ++i) {
        *(float4*)&Wh1[(size_t)(n0 + ti * 4 + i) * (NHEADS * NHID) + h * NHID + tj * 4] =
            make_float4(acc[i][0], acc[i][1], acc[i][2], acc[i][3]);
    }
}

// ---------------- K2: f1/f2 row-dots --------------------------------------------
__global__ __launch_bounds__(256) void k2_f12(const float* __restrict__ Wh1,
                                              const float* __restrict__ a1,
                                              float* __restrict__ f1,
                                              float* __restrict__ f2) {
    const int t = threadIdx.x;
    const int lane = t & 63;
    const int u = blockIdx.x * 4 + (t >> 6);
    const int h = u >> 12;
    const int n = u & (N - 1);
    float v  = Wh1[(size_t)n * 512 + h * 64 + lane];
    float s1 = v * a1[h * 128 + lane];
    float s2 = v * a1[h * 128 + 64 + lane];
    #pragma unroll
    for (int off = 32; off >= 1; off >>= 1) {
        s1 += __shfl_xor(s1, off);
        s2 += __shfl_xor(s2, off);
    }
    if (lane == 0) { f1[h * N + n] = s1; f2[h * N + n] = s2; }
}

// ---------------- K2T: Wh1 f32 [n][h*64+d] -> Wh1T bf16 [h][d][m] ---------------
__global__ __launch_bounds__(256) void k2t_transpose(const float* __restrict__ Wh1,
                                                     u16* __restrict__ Wh1T) {
    __shared__ float ts[64 * 68];   // [m][d], pitch 68
    const int t  = threadIdx.x;
    const int m0 = blockIdx.x * 64;
    const int h  = blockIdx.y;
    #pragma unroll
    for (int i = 0; i < 4; ++i) {
        int flat = t + 256 * i;
        int row = flat >> 4;
        int c4  = (flat & 15) * 4;
        *(float4*)&ts[row * 68 + c4] =
            *(const float4*)&Wh1[(size_t)(m0 + row) * 512 + h * 64 + c4];
    }
    __syncthreads();
    const int d  = t >> 2;
    const int ms = (t & 3) * 16;
    u32 p[8];
    #pragma unroll
    for (int j = 0; j < 8; ++j) {
        float v0 = ts[(ms + 2 * j) * 68 + d];
        float v1 = ts[(ms + 2 * j + 1) * 68 + d];
        p[j] = (u32)f2b(v0) | ((u32)f2b(v1) << 16);
    }
    u32* dst = (u32*)&Wh1T[((size_t)(h * 64 + d)) * 4096 + m0 + ms];
    *(uint4*)dst       = make_uint4(p[0], p[1], p[2], p[3]);
    *(uint4*)(dst + 4) = make_uint4(p[4], p[5], p[6], p[7]);
}

// ---------------- K3: layer-1 attention partials via MFMA -----------------------
// grid (64 n-tiles, 8 heads, 2 m-chunks) x 256; 4 blocks/CU (39.4KB LDS) = 16 waves/CU.
// Writes raw numerator (64 cols) + denominator (ones-col) partials; k3b reduces.
__global__ __launch_bounds__(256, 4) void k3_attn1(const int* __restrict__ adj1,
                                                   const u16* __restrict__ Wh1T,
                                                   const float* __restrict__ f1,
                                                   const float* __restrict__ f2,
                                                   float* __restrict__ pacc1,
                                                   float* __restrict__ pz1) {
    __shared__ u16  wbf[64 * 136];    // A-tile, pitch 136
    __shared__ u16  whT[80 * 136];    // B-tile rows d=0..79 (64 data, 64=ones, 65..79 zero)
    __shared__ float f1s[64];
    const int t     = threadIdx.x;
    const int n0    = blockIdx.x * 64;
    const int h     = blockIdx.y;
    const int chunk = blockIdx.z;
    const int lane  = t & 63;
    const int wrow  = (t >> 6) * 16;
    const int c4    = (t & 31) * 4;           // mask-gen: 4 consecutive cols
    const int rg    = t >> 5;                 // mask-gen: row group 0..7
    if (t < 64) f1s[t] = f1[h * N + n0 + t];
    #pragma unroll
    for (int i = 0; i < 9; ++i) {
        int flat = t + 256 * i;               // rows 64..79: 16*136 = 2176
        if (flat < 16 * 136) {
            int row = 64 + flat / 136;
            whT[row * 136 + (flat % 136)] = (row == 64) ? (u16)0x3F80 : (u16)0;
        }
    }
    f32x4 acc[5];
    #pragma unroll
    for (int df = 0; df < 5; ++df)
        #pragma unroll
        for (int r = 0; r < 4; ++r) acc[df][r] = 0.f;
    __syncthreads();

    const int mbeg = chunk * 2048;
    for (int m0 = mbeg; m0 < mbeg + 2048; m0 += 128) {
        // ---- stage: mask-gen (int4 adj, 8 wide loads/thread) + whT tile ----
        float4 f2v = *(const float4*)&f2[h * N + m0 + c4];
        #pragma unroll
        for (int i = 0; i < 8; ++i) {
            int rr = rg + 8 * i;
            int4 a4 = *(const int4*)&adj1[(size_t)(n0 + rr) * N + m0 + c4];
            float f1v = f1s[rr];
            float w0 = a4.x ? __expf(lrelu(f1v + f2v.x)) : 0.f;
            float w1 = a4.y ? __expf(lrelu(f1v + f2v.y)) : 0.f;
            float w2 = a4.z ? __expf(lrelu(f1v + f2v.z)) : 0.f;
            float w3 = a4.w ? __expf(lrelu(f1v + f2v.w)) : 0.f;
            uint2 pk;
            pk.x = (u32)f2b(w0) | ((u32)f2b(w1) << 16);
            pk.y = (u32)f2b(w2) | ((u32)f2b(w3) << 16);
            *(uint2*)&wbf[rr * 136 + c4] = pk;
        }
        #pragma unroll
        for (int i = 0; i < 4; ++i) {
            int flat = t + 256 * i;           // 64 rows x 16 chunks
            int row = flat >> 4;
            int c8  = (flat & 15) * 8;
            *(uint4*)&whT[row * 136 + c8] =
                *(const uint4*)&Wh1T[((size_t)(h * 64 + row)) * 4096 + m0 + c8];
        }
        __syncthreads();
        // ---- compute: 4 K-steps x 5 d-frags ----
        const int ar   = wrow + (lane & 15);
        const int koff = (lane >> 4) * 8;
        #pragma unroll
        for (int ks = 0; ks < 4; ++ks) {
            int k0 = ks * 32 + koff;
            bf16x8 a = *(const bf16x8*)&wbf[ar * 136 + k0];
            #pragma unroll
            for (int df = 0; df < 5; ++df) {
                bf16x8 b = *(const bf16x8*)&whT[(df * 16 + (lane & 15)) * 136 + k0];
                acc[df] = __builtin_amdgcn_mfma_f32_16x16x32_bf16(a, b, acc[df], 0, 0, 0);
            }
        }
        __syncthreads();
    }
    // ---- epilogue: raw partials ----
    const size_t rowbase = (size_t)(chunk * 8 + h) * 4096 + n0;
    #pragma unroll
    for (int r = 0; r < 4; ++r) {
        int nl = wrow + (lane >> 4) * 4 + r;
        float z = __shfl(acc[4][r], lane & 48);
        if ((lane & 15) == 0) pz1[rowbase + nl] = z;
        #pragma unroll
        for (int df = 0; df < 4; ++df)
            pacc1[(rowbase + nl) * 64 + df * 16 + (lane & 15)] = acc[df][r];
    }
}

// ---------------- K3b: reduce 2 chunks, normalize, ELU -> h1 --------------------
// grid 8192 x 256, one thread per (n,h,d)
__global__ __launch_bounds__(256) void k3b_norm(const float* __restrict__ pacc1,
                                                const float* __restrict__ pz1,
                                                float* __restrict__ h1) {
    const int g = blockIdx.x * 256 + threadIdx.x;
    const int d = g & 63;
    const int h = (g >> 6) & 7;
    const int n = g >> 9;
    const size_t i0 = (size_t)h * 4096 + n;
    float s = pacc1[i0 * 64 + d] + pacc1[(i0 + 8 * 4096) * 64 + d];
    float z = pz1[i0] + pz1[i0 + 8 * 4096];
    float v = s / fmaxf(z, 1e-30f);
    h1[(size_t)n * 512 + h * 64 + d] = v > 0.f ? v : __expf(v) - 1.f;
}

// ---------------- K4: Wh2[n][c] = h1[n,:] @ Wo[:,c]  (f32) ----------------------
__global__ __launch_bounds__(256) void k4_gemm2(const float* __restrict__ h1,
                                                const float* __restrict__ Wo,
                                                float* __restrict__ Wh2) {
    const int t = threadIdx.x;
    const int c = t & 63;
    const int n = blockIdx.x * 4 + (t >> 6);
    if (c < NCLASS) {
        const float* hrow = &h1[(size_t)n * 512];
        float acc = 0.f;
        #pragma unroll 8
        for (int f = 0; f < 512; ++f)
            acc += hrow[f] * Wo[f * NCLASS + c];
        Wh2[(size_t)n * NCLASS + c] = acc;
    }
}

// ---------------- K4b: f1o/f2o + Wh2T bf16 [c][n] -------------------------------
__global__ __launch_bounds__(256) void k4b_fo(const float* __restrict__ Wh2,
                                              const float* __restrict__ ao,
                                              float* __restrict__ f1o,
                                              float* __restrict__ f2o,
                                              u16* __restrict__ Wh2T) {
    const int n = blockIdx.x * 256 + threadIdx.x;
    float s1 = 0.f, s2 = 0.f;
    #pragma unroll
    for (int c = 0; c < NCLASS; ++c) {
        float v = Wh2[(size_t)n * NCLASS + c];
        s1 += v * ao[c];
        s2 += v * ao[NCLASS + c];
        Wh2T[(size_t)c * 4096 + n] = f2b(v);
    }
    f1o[n] = s1; f2o[n] = s2;
}

// ---------------- K5a: layer-2 attention partials via MFMA ----------------------
// grid (64 n-tiles, 16 m-chunks) x 256; 4 blocks/CU. d-frags: 0..39 data, 48 = ones.
__global__ __launch_bounds__(256, 4) void k5a_attn2(const int* __restrict__ adj0,
                                                    const u16* __restrict__ Wh2T,
                                                    const float* __restrict__ f1o,
                                                    const float* __restrict__ f2o,
                                                    float* __restrict__ pacc,
                                                    float* __restrict__ pz) {
    __shared__ u16  wbf[64 * 136];
    __shared__ u16  whT[64 * 136];    // rows 0..39 data, 48 ones, others zero
    __shared__ float f1s[64];
    const int t     = threadIdx.x;
    const int n0    = blockIdx.x * 64;
    const int chunk = blockIdx.y;
    const int mbase = chunk * 256;
    const int lane  = t & 63;
    const int wrow  = (t >> 6) * 16;
    const int c4    = (t & 31) * 4;
    const int rg    = t >> 5;
    if (t < 64) f1s[t] = f1o[n0 + t];
    #pragma unroll
    for (int i = 0; i < 13; ++i) {
        int flat = t + 256 * i;               // rows 40..63: 24*136 = 3264
        if (flat < 24 * 136) {
            int row = 40 + flat / 136;
            whT[row * 136 + (flat % 136)] = (row == 48) ? (u16)0x3F80 : (u16)0;
        }
    }
    f32x4 acc[4];
    #pragma unroll
    for (int df = 0; df < 4; ++df)
        #pragma unroll
        for (int r = 0; r < 4; ++r) acc[df][r] = 0.f;
    __syncthreads();

    for (int mt = 0; mt < 2; ++mt) {
        int m0 = mbase + mt * 128;
        float4 f2v = *(const float4*)&f2o[m0 + c4];
        #pragma unroll
        for (int i = 0; i < 8; ++i) {
            int rr = rg + 8 * i;
            int4 a4 = *(const int4*)&adj0[(size_t)(n0 + rr) * N + m0 + c4];
            float f1v = f1s[rr];
            float w0 = a4.x ? __expf(lrelu(f1v + f2v.x)) : 0.f;
            float w1 = a4.y ? __expf(lrelu(f1v + f2v.y)) : 0.f;
            float w2 = a4.z ? __expf(lrelu(f1v + f2v.z)) : 0.f;
            float w3 = a4.w ? __expf(lrelu(f1v + f2v.w)) : 0.f;
            uint2 pk;
            pk.x = (u32)f2b(w0) | ((u32)f2b(w1) << 16);
            pk.y = (u32)f2b(w2) | ((u32)f2b(w3) << 16);
            *(uint2*)&wbf[rr * 136 + c4] = pk;
        }
        #pragma unroll
        for (int i = 0; i < 3; ++i) {
            int flat = t + 256 * i;           // 40 rows x 16 chunks = 640
            if (flat < 640) {
                int row = flat >> 4;
                int c8  = (flat & 15) * 8;
                *(uint4*)&whT[row * 136 + c8] =
                    *(const uint4*)&Wh2T[(size_t)row * 4096 + m0 + c8];
            }
        }
        __syncthreads();
        const int ar   = wrow + (lane & 15);
        const int koff = (lane >> 4) * 8;
        #pragma unroll
        for (int ks = 0; ks < 4; ++ks) {
            int k0 = ks * 32 + koff;
            bf16x8 a = *(const bf16x8*)&wbf[ar * 136 + k0];
            #pragma unroll
            for (int df = 0; df < 4; ++df) {
                bf16x8 b = *(const bf16x8*)&whT[(df * 16 + (lane & 15)) * 136 + k0];
                acc[df] = __builtin_amdgcn_mfma_f32_16x16x32_bf16(a, b, acc[df], 0, 0, 0);
            }
        }
        __syncthreads();
    }
    // store raw partials (numerator cols 0..39, denominator col 48)
    #pragma unroll
    for (int r = 0; r < 4; ++r) {
        int n = n0 + wrow + (lane >> 4) * 4 + r;
        float z = __shfl(acc[3][r], lane & 48);
        if ((lane & 15) == 0) pz[(size_t)chunk * N + n] = z;
        #pragma unroll
        for (int df = 0; df < 3; ++df) {
            int c = df * 16 + (lane & 15);
            if (c < NCLASS)
                pacc[((size_t)chunk * N + n) * NCLASS + c] = acc[df][r];
        }
    }
}

// ---------------- K5b: reduce 16 chunks, ELU, log_softmax, f32 store ------------
__global__ __launch_bounds__(256) void k5b_final(const float* __restrict__ pacc,
                                                 const float* __restrict__ pz,
                                                 float* __restrict__ out) {
    const int t = threadIdx.x;
    const int lane = t & 63;
    const int n = blockIdx.x * 4 + (t >> 6);
    float s = 0.f, Z = 0.f;
    #pragma unroll
    for (int ch = 0; ch < 16; ++ch) {
        Z += pz[(size_t)ch * N + n];
        if (lane < NCLASS) s += pacc[((size_t)ch * N + n) * NCLASS + lane];
    }
    float v;
    if (lane < NCLASS) {
        v = s / fmaxf(Z, 1e-30f);
        v = v > 0.f ? v : __expf(v) - 1.f;
    } else {
        v = -INFINITY;
    }
    float mx = v;
    #pragma unroll
    for (int off = 32; off >= 1; off >>= 1) mx = fmaxf(mx, __shfl_xor(mx, off));
    float ex = (lane < NCLASS) ? __expf(v - mx) : 0.f;
    #pragma unroll
    for (int off = 32; off >= 1; off >>= 1) ex += __shfl_xor(ex, off);
    float lse = mx + __logf(ex);
    if (lane < NCLASS) out[(size_t)n * NCLASS + lane] = v - lse;
}

// ---------------------------------------------------------------------------------
// Workspace layout (f32 units), lifetime-aliased region R at the end:
//   R holds Wh1 (k1->k2t), then pacc1 (k3->k3b), then pacc (k5a->k5b) - disjoint lifetimes.
extern "C" void kernel_launch(void* const* d_in, const int* in_sizes, int n_in,
                              void* d_out, int out_size, void* d_ws, size_t ws_size,
                              hipStream_t stream) {
    const float* x   = (const float*)d_in[0];
    const int*   adj = (const int*)d_in[1];
    const float* W1  = (const float*)d_in[2];
    const float* a1  = (const float*)d_in[3];
    const float* Wo  = (const float*)d_in[4];
    const float* ao  = (const float*)d_in[5];

    float* ws    = (float*)d_ws;
    float* h1    = ws;                        // 2,097,152
    float* f1    = h1 + 2097152;              // 32,768
    float* f2    = f1 + 32768;                // 32,768
    float* Wh2   = f2 + 32768;                // 163,840
    float* f1o   = Wh2 + 163840;              // 4,096
    float* f2o   = f1o + 4096;                // 4,096
    float* pz    = f2o + 4096;                // 65,536 (16*4096, k5a)
    float* pz1   = pz + 65536;                // 65,536 (2*8*4096, k3)
    u16*   Wh1T  = (u16*)(pz1 + 65536);       // 2,097,152 u16 (1,048,576 slots)
    u16*   Wh2T  = Wh1T + 2097152;            // 163,840 u16 (81,920 slots)
    float* R     = (float*)(Wh2T + 163840);   // 4,194,304 f32 shared region
    float* Wh1   = R;                         // k1 -> k2/k2t
    float* pacc1 = R;                         // k3 -> k3b (2*8*4096*64)
    float* pacc  = R;                         // k5a -> k5b (16*4096*40)
    // total = 7,790,592 f32 ~= 29.7 MiB

    const int* adj0 = adj;                    // layer-2 mask
    const int* adj1 = adj + (size_t)N * N;    // layer-1 mask

    hipLaunchKernelGGL(k1_gemm1,      dim3(64, 8),    dim3(256), 0, stream, x, W1, Wh1);
    hipLaunchKernelGGL(k2_f12,        dim3(8192),     dim3(256), 0, stream, Wh1, a1, f1, f2);
    hipLaunchKernelGGL(k2t_transpose, dim3(64, 8),    dim3(256), 0, stream, Wh1, Wh1T);
    hipLaunchKernelGGL(k3_attn1,      dim3(64, 8, 2), dim3(256), 0, stream, adj1, Wh1T, f1, f2, pacc1, pz1);
    hipLaunchKernelGGL(k3b_norm,      dim3(8192),     dim3(256), 0, stream, pacc1, pz1, h1);
    hipLaunchKernelGGL(k4_gemm2,      dim3(1024),     dim3(256), 0, stream, h1, Wo, Wh2);
    hipLaunchKernelGGL(k4b_fo,        dim3(16),       dim3(256), 0, stream, Wh2, ao, f1o, f2o, Wh2T);
    hipLaunchKernelGGL(k5a_attn2,     dim3(64, 16),   dim3(256), 0, stream, adj0, Wh2T, f1o, f2o, pacc, pz);
    hipLaunchKernelGGL(k5b_final,     dim3(1024),     dim3(256), 0, stream, pacc, pz, (float*)d_out);
}